// Round 8
// baseline (203.841 us; speedup 1.0000x reference)
//
#include <hip/hip_runtime.h>
#include <hip/hip_bf16.h>
#include <hip/hip_cooperative_groups.h>
#include <cstdio>

namespace cg = cooperative_groups;

// Problem constants: B=2, S=1024, D=256, H=8, K=32
#define PB 2
#define PS 1024
#define PD 256
#define PK 32
#define PH 8
#define HB (PH*PB)          // 16
#define BS (PB*PS)          // 2048
#define EPS 1e-9f

typedef __attribute__((ext_vector_type(8))) short bf16x8;
typedef __attribute__((ext_vector_type(4))) float f32x4;

__device__ inline unsigned short f2bf(float f) {
    __hip_bfloat16 h = __float2bfloat16(f);
    return *reinterpret_cast<unsigned short*>(&h);
}
__device__ inline float bf2f(unsigned short u) {
    return __bfloat162float(*reinterpret_cast<__hip_bfloat16*>(&u));
}

// ---------------- kernel 1: fused prep (xb, WqT, WkT, WvT, WoT) --------------
__global__ __launch_bounds__(256) void k_prep(
    const float* __restrict__ x, const float* __restrict__ Wqs,
    const float* __restrict__ Wks, const float* __restrict__ Wvs,
    const float* __restrict__ Wo,
    unsigned short* __restrict__ xb, unsigned short* __restrict__ WqT,
    unsigned short* __restrict__ WkT, unsigned short* __restrict__ WvT,
    unsigned short* __restrict__ WoT)
{
    __shared__ float smem[8448];
    int bid = blockIdx.x, tid = threadIdx.x;
    if (bid < 512) {                       // xb: f32 -> bf16
        int i = bid*256 + tid;
        float4 v = ((const float4*)x)[i];
        ushort4 o = {f2bf(v.x), f2bf(v.y), f2bf(v.z), f2bf(v.w)};
        ((ushort4*)xb)[i] = o;
        return;
    }
    if (bid < 528) {                       // Wq/Wk [d 256][kk 32] -> [kk][d]
        int r2 = bid - 512;
        int h = r2 >> 1, isK = r2 & 1;
        const float* S = (isK ? Wks : Wqs) + (size_t)h*8192;
        unsigned short* D = (isK ? WkT : WqT) + (size_t)h*8192;
#pragma unroll
        for (int p = 0; p < 32; ++p) {
            int idx = p*256 + tid;                  // d*32 + kk
            smem[(idx>>5)*33 + (idx&31)] = S[idx];
        }
        __syncthreads();
#pragma unroll
        for (int p = 0; p < 8; ++p) {
            int o4 = p*256 + tid;                   // kk*256 + d (ushort4 granule)
            int kk = o4 >> 6, d = (o4 & 63)*4;
            ushort4 o;
            o.x = f2bf(smem[(d+0)*33 + kk]); o.y = f2bf(smem[(d+1)*33 + kk]);
            o.z = f2bf(smem[(d+2)*33 + kk]); o.w = f2bf(smem[(d+3)*33 + kk]);
            *(ushort4*)(D + (size_t)kk*256 + d) = o;
        }
        return;
    }
    // 256x256 per-head transposes
    int r3 = bid - 528;
    const float* S; unsigned short* dst; int rs, hs;
    if (r3 < 128) { S = Wvs; dst = WvT; rs = 256;  hs = 65536; }
    else          { r3 -= 128; S = Wo; dst = WoT; rs = 2048; hs = 256; }
    int e0 = (r3 & 3)*64, d0 = ((r3>>2) & 3)*64, h = r3 >> 4;
    float (*T)[69] = (float(*)[69])smem;
    const float* Sh = S + (size_t)h*65536;
    int ty = tid>>4, c4 = tid&15;
#pragma unroll
    for (int p = 0; p < 4; ++p) {
        int r = p*16 + ty;
        float4 v = *(const float4*)(Sh + (size_t)(d0+r)*256 + e0 + c4*4);
        T[r][c4*4+0]=v.x; T[r][c4*4+1]=v.y; T[r][c4*4+2]=v.z; T[r][c4*4+3]=v.w;
    }
    __syncthreads();
    unsigned short* D = dst + (size_t)h*hs;
#pragma unroll
    for (int p = 0; p < 4; ++p) {
        int er = p*16 + ty;
        ushort4 o;
        o.x = f2bf(T[c4*4+0][er]); o.y = f2bf(T[c4*4+1][er]);
        o.z = f2bf(T[c4*4+2][er]); o.w = f2bf(T[c4*4+3][er]);
        *(ushort4*)(D + (size_t)(e0+er)*rs + d0 + c4*4) = o;
    }
}

// ---------------- kernel 2: all projections via MFMA -------------------------
__global__ __launch_bounds__(256) void k_proj(
    const unsigned short* __restrict__ xb, const unsigned short* __restrict__ WqT,
    const unsigned short* __restrict__ WkT, const unsigned short* __restrict__ WvT,
    unsigned short* __restrict__ Qb, unsigned short* __restrict__ Kb,
    unsigned short* __restrict__ Vt)
{
    int z = blockIdx.z;
    int m0 = blockIdx.y*64, n0 = blockIdx.x*64;
    int tid = threadIdx.x, w = tid>>6, l15 = tid&15, g = (tid>>4)&3;
    f32x4 zf = {0.f,0.f,0.f,0.f};
    f32x4 acc[4] = {zf,zf,zf,zf};
    const unsigned short* arow = xb + (size_t)(m0+16*w+l15)*256 + 8*g;
    const unsigned short* W;
    if (z < 8)       W = WvT + (size_t)z*65536;
    else if (z == 8) W = WqT;
    else             W = WkT;
#pragma unroll
    for (int kk = 0; kk < 8; ++kk) {
        bf16x8 af = *(const bf16x8*)(arow + kk*32);
#pragma unroll
        for (int nt = 0; nt < 4; ++nt) {
            bf16x8 bf = *(const bf16x8*)(W + (size_t)(n0+16*nt+l15)*256 + kk*32 + 8*g);
            acc[nt] = __builtin_amdgcn_mfma_f32_16x16x32_bf16(af, bf, acc[nt], 0, 0, 0);
        }
    }
    if (z < 8) {                       // Vt[h*32+bsTile][e][t]
        unsigned short* VtT = Vt + ((size_t)z*32 + blockIdx.y)*(256*64);
#pragma unroll
        for (int nt = 0; nt < 4; ++nt) {
            ushort4 o = {f2bf(acc[nt][0]), f2bf(acc[nt][1]), f2bf(acc[nt][2]), f2bf(acc[nt][3])};
            *(ushort4*)(VtT + (size_t)(n0+16*nt+l15)*64 + 16*w + 4*g) = o;
        }
    } else {
        unsigned short* dst = (z == 8) ? Qb : Kb;
        int bs_base = m0 + 16*w + 4*g;
#pragma unroll
        for (int nt = 0; nt < 4; ++nt) {
            int col = n0 + 16*nt + l15;             // h*32 + kk
            int h = col>>5, kk = col&31;
#pragma unroll
            for (int j = 0; j < 4; ++j) {
                int bs = bs_base + j;
                int b = bs>>10, s = bs&1023;
                float zv = acc[nt][j];
                zv = zv > 0.f ? zv + 1.f : expf(zv);
                dst[((size_t)(h*PB+b)*PS + s)*PK + kk] = f2bf(zv);
            }
        }
    }
}

// ---------------- kernel 3: cooperative mega-kernel --------------------------
// grid (c 16, hb 16) x 512 threads. Phases:
//  1 chunk KV+K sums -> gsync -> 2 KV scan -> gsync ->
//  3 den (rden in LDS) -> 4 att strip incl diag (PL in LDS) -> 5 node ->
//  gsync -> 6 out GEMM (2 tiles/block)
__global__ __launch_bounds__(512) void k_mega(
    const unsigned short* __restrict__ Qb, const unsigned short* __restrict__ Kb,
    const unsigned short* __restrict__ Vt,
    float* __restrict__ KVs, float* __restrict__ KsumG,
    unsigned short* __restrict__ KVpre,
    float* __restrict__ att, unsigned short* __restrict__ nodeB,
    const unsigned short* __restrict__ WoT, float* __restrict__ out)
{
    cg::grid_group grid = cg::this_grid();
    int c = blockIdx.x, hb = blockIdx.y;
    int tid = threadIdx.x;
    int w = tid >> 6, l15 = tid & 15, g = (tid >> 4) & 3;
    f32x4 zf = {0.f, 0.f, 0.f, 0.f};

    __shared__ __align__(16) unsigned char smem[26880];
    unsigned short* PL   = (unsigned short*)smem;            // [0,9216)
    float* rden          = (float*)(smem + 9216);            // [9216,9472)
    unsigned short* KT   = (unsigned short*)(smem + 9472);   // 4608 (phase1)
    float* partial       = (float*)(smem + 9472 + 4608);     // 1024 (phase1)
    float (*kc)[33]      = (float(*)[33])(smem + 9472);      // 8448 (phase3)
    float (*PT)[68]      = (float(*)[68])(smem + 9472);      // 17408 (phase4)

    const unsigned short* Vtt = Vt + ((size_t)hb*16 + c)*(256*64);

    // ---------------- phase 1: chunk KV sums (MFMA) + K sums ----------------
#pragma unroll
    for (int i = 0; i < 4; ++i) {
        int flat = tid + i*512;                 // t = flat>>5, k = flat&31
        KT[(flat&31)*72 + (flat>>5)] = Kb[((size_t)hb*PS + c*64 + (flat>>5))*PK + (flat&31)];
    }
    __syncthreads();
    if (tid < 256) {
        int kk = tid & 31, part = tid >> 5;
        float s = 0.f;
#pragma unroll
        for (int i = 0; i < 8; ++i) s += bf2f(KT[kk*72 + part*8 + i]);
        partial[part*32 + kk] = s;
    }
    {
        f32x4 acc1[2][2];
        acc1[0][0]=zf; acc1[0][1]=zf; acc1[1][0]=zf; acc1[1][1]=zf;
#pragma unroll
        for (int ks = 0; ks < 2; ++ks) {
            bf16x8 af[2];
#pragma unroll
            for (int mt = 0; mt < 2; ++mt)
                af[mt] = *(const bf16x8*)(Vtt + (size_t)(32*w + 16*mt + l15)*64 + 32*ks + 8*g);
#pragma unroll
            for (int nt = 0; nt < 2; ++nt) {
                bf16x8 bf = *(const bf16x8*)(KT + (16*nt + l15)*72 + 32*ks + 8*g);
#pragma unroll
                for (int mt = 0; mt < 2; ++mt)
                    acc1[mt][nt] = __builtin_amdgcn_mfma_f32_16x16x32_bf16(af[mt], bf, acc1[mt][nt], 0, 0, 0);
            }
        }
        __syncthreads();
        if (tid < 32) {
            float s = 0.f;
#pragma unroll
            for (int p = 0; p < 8; ++p) s += partial[p*32 + tid];
            KsumG[((size_t)hb*16 + c)*32 + tid] = s;
        }
        float* o = KVs + ((size_t)hb*16 + c)*8192;
#pragma unroll
        for (int mt = 0; mt < 2; ++mt)
#pragma unroll
            for (int nt = 0; nt < 2; ++nt)
#pragma unroll
                for (int j = 0; j < 4; ++j)
                    o[(size_t)(32*w + 16*mt + 4*g + j)*32 + 16*nt + l15] = acc1[mt][nt][j];
    }
    grid.sync();

    // ---------------- phase 2: exclusive KV scan over chunks -> bf16 --------
    {
        int i = c*512 + tid;                    // 0..8191 = e*32+k
        const float* src = KVs + (size_t)hb*16*8192 + i;
        unsigned short* dst = KVpre + (size_t)hb*16*8192 + i;
        float acc = 0.f;
#pragma unroll
        for (int cc = 0; cc < 16; ++cc) { dst[cc*8192] = f2bf(acc); acc += src[cc*8192]; }
    }
    grid.sync();

    // ---------------- phase 3: den -> rden in LDS ---------------------------
    {
        bool act = tid < 256;
        int r = tid >> 2, quad = tid & 3;
        if (act) {
            bf16x8 k8 = *(const bf16x8*)(Kb + ((size_t)hb*PS + c*64 + r)*PK + quad*8);
#pragma unroll
            for (int i = 0; i < 8; ++i) kc[r][quad*8+i] = bf2f((unsigned short)k8[i]);
        }
        __syncthreads();
#pragma unroll
        for (int st = 1; st < 64; st <<= 1) {
            float tmp[8];
            if (act) {
#pragma unroll
                for (int i = 0; i < 8; ++i) tmp[i] = (r >= st) ? kc[r-st][quad*8+i] : 0.f;
            }
            __syncthreads();
            if (act) {
#pragma unroll
                for (int i = 0; i < 8; ++i) kc[r][quad*8+i] += tmp[i];
            }
            __syncthreads();
        }
        if (act) {
            float kp[8];
#pragma unroll
            for (int i = 0; i < 8; ++i) kp[i] = 0.f;
            for (int cc = 0; cc < c; ++cc) {
                const float* Ks = KsumG + ((size_t)hb*16 + cc)*32 + quad*8;
#pragma unroll
                for (int i = 0; i < 8; ++i) kp[i] += Ks[i];
            }
            bf16x8 q8 = *(const bf16x8*)(Qb + ((size_t)hb*PS + c*64 + r)*PK + quad*8);
            float p = 0.f;
#pragma unroll
            for (int i = 0; i < 8; ++i)
                p += bf2f((unsigned short)q8[i]) * (kp[i] + kc[r][quad*8+i]);
            p += __shfl_xor(p, 1);
            p += __shfl_xor(p, 2);
            if (quad == 0) rden[r] = 1.0f / (p + EPS);
        }
        __syncthreads();
    }

    // ---------------- phase 4: att strip (zeros + lower + diag) -------------
    int s0 = c*64;
    float* attb = att + (size_t)hb*PS*PS;
    {
        // zero rectangle rows [s0,s0+64) cols [s0+64,1024)
        int c0 = s0 + 64;
        int nzf4 = (PS - c0) >> 2;
        int col = tid & 255, half = tid >> 8;
        if (col < nzf4) {
            float4 z = {0.f,0.f,0.f,0.f};
            float* zb = attb + (size_t)(s0 + 32*half)*PS + c0 + col*4;
#pragma unroll 4
            for (int r = 0; r < 32; ++r)
                *(float4*)(zb + (size_t)r*PS) = z;
        }
        int ws = w & 3, eh = w >> 2;
        bf16x8 qf = *(const bf16x8*)(Qb + ((size_t)hb*PS + s0 + 16*ws + l15)*PK + 8*g);
        float rd[4];
#pragma unroll
        for (int j = 0; j < 4; ++j) rd[j] = rden[16*ws + 4*g + j];
        // strictly-lower tiles
        for (int tt = 0; tt < c; ++tt) {
            int t0 = tt*64;
            f32x4 p[2];
#pragma unroll
            for (int i = 0; i < 2; ++i) {
                int nt = eh*2 + i;
                bf16x8 kf = *(const bf16x8*)(Kb + ((size_t)hb*PS + t0 + 16*nt + l15)*PK + 8*g);
                p[i] = __builtin_amdgcn_mfma_f32_16x16x32_bf16(qf, kf, zf, 0, 0, 0);
            }
#pragma unroll
            for (int i = 0; i < 2; ++i) {
                int nt = eh*2 + i;
#pragma unroll
                for (int j = 0; j < 4; ++j)
                    PT[16*ws + 4*g + j][16*nt + l15] = p[i][j] * rd[j];
            }
            __syncthreads();
#pragma unroll
            for (int pp = 0; pp < 2; ++pp) {
                int f4 = tid + pp*512;
                int r = f4 >> 4, c4 = f4 & 15;
                float4 v = *(const float4*)&PT[r][c4*4];
                *(float4*)(attb + (size_t)(s0+r)*PS + t0 + c4*4) = v;
            }
            __syncthreads();
        }
        // diagonal tile (masked) + PL
        {
            f32x4 p[2];
#pragma unroll
            for (int i = 0; i < 2; ++i) {
                int nt = eh*2 + i;
                bf16x8 kf = *(const bf16x8*)(Kb + ((size_t)hb*PS + s0 + 16*nt + l15)*PK + 8*g);
                p[i] = __builtin_amdgcn_mfma_f32_16x16x32_bf16(qf, kf, zf, 0, 0, 0);
            }
#pragma unroll
            for (int i = 0; i < 2; ++i) {
                int nt = eh*2 + i;
                int tc = 16*nt + l15;
#pragma unroll
                for (int j = 0; j < 4; ++j) {
                    int r = 16*ws + 4*g + j;
                    float v = p[i][j] * rd[j];
                    if (tc > r) v = 0.f;
                    PT[r][tc] = v;
                    PL[r*72 + tc] = f2bf(v);
                }
            }
            __syncthreads();
#pragma unroll
            for (int pp = 0; pp < 2; ++pp) {
                int f4 = tid + pp*512;
                int r = f4 >> 4, c4 = f4 & 15;
                float4 v = *(const float4*)&PT[r][c4*4];
                *(float4*)(attb + (size_t)(s0+r)*PS + s0 + c4*4) = v;
            }
            __syncthreads();
        }
    }

    // ---------------- phase 5: node = rden*(q.KVpre) + P@V -> nodeB ---------
    {
        int ws = w & 3, eh = w >> 2;
        bf16x8 qf = *(const bf16x8*)(Qb + ((size_t)hb*PS + s0 + 16*ws + l15)*PK + 8*g);
        const unsigned short* KVp = KVpre + ((size_t)hb*16 + c)*8192;
        f32x4 acc[8];
#pragma unroll
        for (int nt = 0; nt < 8; ++nt) {
            int tile = eh*8 + nt;
            bf16x8 bf = *(const bf16x8*)(KVp + (size_t)(16*tile + l15)*32 + 8*g);
            acc[nt] = __builtin_amdgcn_mfma_f32_16x16x32_bf16(qf, bf, zf, 0, 0, 0);
        }
        float rd[4];
#pragma unroll
        for (int j = 0; j < 4; ++j) rd[j] = rden[16*ws + 4*g + j];
#pragma unroll
        for (int nt = 0; nt < 8; ++nt)
#pragma unroll
            for (int j = 0; j < 4; ++j) acc[nt][j] *= rd[j];
#pragma unroll
        for (int ks = 0; ks < 2; ++ks) {
            bf16x8 af = *(const bf16x8*)(PL + (size_t)(16*ws + l15)*72 + 32*ks + 8*g);
#pragma unroll
            for (int nt = 0; nt < 8; ++nt) {
                int tile = eh*8 + nt;
                bf16x8 vf = *(const bf16x8*)(Vtt + (size_t)(16*tile + l15)*64 + 32*ks + 8*g);
                acc[nt] = __builtin_amdgcn_mfma_f32_16x16x32_bf16(af, vf, acc[nt], 0, 0, 0);
            }
        }
        int h = hb >> 1, b = hb & 1;
        unsigned short* np = nodeB + ((size_t)(b*PS + s0))*2048 + h*256;
#pragma unroll
        for (int nt = 0; nt < 8; ++nt)
#pragma unroll
            for (int j = 0; j < 4; ++j)
                np[(size_t)(16*ws + 4*g + j)*2048 + 16*(eh*8 + nt) + l15] = f2bf(acc[nt][j]);
    }
    grid.sync();

    // ---------------- phase 6: out = nodeB @ WoT (2 tiles per block) --------
    {
        int t = (blockIdx.y*16 + blockIdx.x)*2 + (tid >> 8);
        int e0 = (t & 3)*64, m0 = (t >> 2)*16;
        int tid2 = tid & 255;
        int w2 = tid2 >> 6, l15b = tid2 & 15, g2 = (tid2 >> 4) & 3;
        f32x4 acc = zf;
        const unsigned short* arow = nodeB + (size_t)(m0 + l15b)*2048 + 8*g2;
        const unsigned short* brow = WoT + (size_t)(e0 + 16*w2 + l15b)*2048 + 8*g2;
#pragma unroll 8
        for (int kk = 0; kk < 64; ++kk) {
            bf16x8 af = *(const bf16x8*)(arow + kk*32);
            bf16x8 bf = *(const bf16x8*)(brow + kk*32);
            acc = __builtin_amdgcn_mfma_f32_16x16x32_bf16(af, bf, acc, 0, 0, 0);
        }
#pragma unroll
        for (int j = 0; j < 4; ++j)
            out[(size_t)(m0 + 4*g2 + j)*PD + e0 + 16*w2 + l15b] = acc[j];
    }
}

// ---------------- launch ------------------------------------------------------
extern "C" void kernel_launch(void* const* d_in, const int* in_sizes, int n_in,
                              void* d_out, int out_size, void* d_ws, size_t ws_size,
                              hipStream_t stream) {
    const float* x   = (const float*)d_in[0];
    const float* Wks = (const float*)d_in[1];
    const float* Wqs = (const float*)d_in[2];
    const float* Wvs = (const float*)d_in[3];
    const float* Wo  = (const float*)d_in[4];

    float* out = (float*)d_out;                     // [B,S,D]
    float* att = (float*)d_out + (size_t)PB*PS*PD;  // [H,B,S,S]

    // workspace layout (float offsets)
    float* ws = (float*)d_ws;
    unsigned short* Qb    = (unsigned short*)(ws + 0);         //   524,288 u16
    unsigned short* Kb    = (unsigned short*)(ws + 262144);    //   524,288 u16
    unsigned short* Vt    = (unsigned short*)(ws + 524288);    // 4,194,304 u16
    unsigned short* xb    = (unsigned short*)(ws + 2621440);   //   524,288 u16
    unsigned short* WqT   = (unsigned short*)(ws + 2883584);   //    65,536 u16
    unsigned short* WkT   = (unsigned short*)(ws + 2916352);   //    65,536 u16
    unsigned short* WvT   = (unsigned short*)(ws + 2949120);   //   524,288 u16
    unsigned short* WoT   = (unsigned short*)(ws + 3211264);   //   524,288 u16
    unsigned short* nodeB = (unsigned short*)(ws + 3473408);   // 4,194,304 u16
    float*          KVs   = ws + 5570560;                      // 2,097,152 f
    unsigned short* KVpre = (unsigned short*)(ws + 7667712);   // 2,097,152 u16
    float*          KsumG = ws + 8716288;                      //     8,192 f
    const size_t needed = (size_t)8724480 * 4;
    if (ws_size < needed) {
        fprintf(stderr, "kernel_launch: ws_size %zu < needed %zu\n", ws_size, needed);
        return;
    }

    k_prep<<<784, 256, 0, stream>>>(x, Wqs, Wks, Wvs, Wo, xb, WqT, WkT, WvT, WoT);
    k_proj<<<dim3(4, 32, 10), 256, 0, stream>>>(xb, WqT, WkT, WvT, Qb, Kb, Vt);

    void* kargs[] = {
        (void*)&Qb, (void*)&Kb, (void*)&Vt,
        (void*)&KVs, (void*)&KsumG, (void*)&KVpre,
        (void*)&att, (void*)&nodeB, (void*)&WoT, (void*)&out
    };
    hipLaunchCooperativeKernel((void*)k_mega, dim3(16, 16), dim3(512, 1, 1),
                               kargs, 0, stream);
}

// Round 9
// 102.327 us; speedup vs baseline: 1.9921x; 1.9921x over previous
//
#include <hip/hip_runtime.h>
#include <hip/hip_bf16.h>
#include <cstdio>

// Problem constants: B=2, S=1024, D=256, H=8, K=32
#define PB 2
#define PS 1024
#define PD 256
#define PK 32
#define PH 8
#define HB (PH*PB)          // 16
#define BS (PB*PS)          // 2048
#define EPS 1e-9f

typedef __attribute__((ext_vector_type(8))) short bf16x8;
typedef __attribute__((ext_vector_type(4))) float f32x4;

__device__ inline unsigned short f2bf(float f) {
    __hip_bfloat16 h = __float2bfloat16(f);
    return *reinterpret_cast<unsigned short*>(&h);
}
__device__ inline float bf2f(unsigned short u) {
    return __bfloat162float(*reinterpret_cast<__hip_bfloat16*>(&u));
}

// ---------------- kernel 1: fused prep (xb, WqT, WkT, WvT, WoT) --------------
__global__ __launch_bounds__(256) void k_prep(
    const float* __restrict__ x, const float* __restrict__ Wqs,
    const float* __restrict__ Wks, const float* __restrict__ Wvs,
    const float* __restrict__ Wo,
    unsigned short* __restrict__ xb, unsigned short* __restrict__ WqT,
    unsigned short* __restrict__ WkT, unsigned short* __restrict__ WvT,
    unsigned short* __restrict__ WoT)
{
    __shared__ float smem[8448];
    int bid = blockIdx.x, tid = threadIdx.x;
    if (bid < 512) {                       // xb: f32 -> bf16
        int i = bid*256 + tid;
        float4 v = ((const float4*)x)[i];
        ushort4 o = {f2bf(v.x), f2bf(v.y), f2bf(v.z), f2bf(v.w)};
        ((ushort4*)xb)[i] = o;
        return;
    }
    if (bid < 528) {                       // Wq/Wk [d 256][kk 32] -> [kk][d]
        int r2 = bid - 512;
        int h = r2 >> 1, isK = r2 & 1;
        const float* S = (isK ? Wks : Wqs) + (size_t)h*8192;
        unsigned short* D = (isK ? WkT : WqT) + (size_t)h*8192;
#pragma unroll
        for (int p = 0; p < 32; ++p) {
            int idx = p*256 + tid;                  // d*32 + kk
            smem[(idx>>5)*33 + (idx&31)] = S[idx];
        }
        __syncthreads();
#pragma unroll
        for (int p = 0; p < 8; ++p) {
            int o4 = p*256 + tid;                   // kk*256 + d (ushort4 granule)
            int kk = o4 >> 6, d = (o4 & 63)*4;
            ushort4 o;
            o.x = f2bf(smem[(d+0)*33 + kk]); o.y = f2bf(smem[(d+1)*33 + kk]);
            o.z = f2bf(smem[(d+2)*33 + kk]); o.w = f2bf(smem[(d+3)*33 + kk]);
            *(ushort4*)(D + (size_t)kk*256 + d) = o;
        }
        return;
    }
    // 256x256 per-head transposes
    int r3 = bid - 528;
    const float* S; unsigned short* dst; int rs, hs;
    if (r3 < 128) { S = Wvs; dst = WvT; rs = 256;  hs = 65536; }
    else          { r3 -= 128; S = Wo; dst = WoT; rs = 2048; hs = 256; }
    int e0 = (r3 & 3)*64, d0 = ((r3>>2) & 3)*64, h = r3 >> 4;
    float (*T)[69] = (float(*)[69])smem;
    const float* Sh = S + (size_t)h*65536;
    int ty = tid>>4, c4 = tid&15;
#pragma unroll
    for (int p = 0; p < 4; ++p) {
        int r = p*16 + ty;
        float4 v = *(const float4*)(Sh + (size_t)(d0+r)*256 + e0 + c4*4);
        T[r][c4*4+0]=v.x; T[r][c4*4+1]=v.y; T[r][c4*4+2]=v.z; T[r][c4*4+3]=v.w;
    }
    __syncthreads();
    unsigned short* D = dst + (size_t)h*hs;
#pragma unroll
    for (int p = 0; p < 4; ++p) {
        int er = p*16 + ty;
        ushort4 o;
        o.x = f2bf(T[c4*4+0][er]); o.y = f2bf(T[c4*4+1][er]);
        o.z = f2bf(T[c4*4+2][er]); o.w = f2bf(T[c4*4+3][er]);
        *(ushort4*)(D + (size_t)(e0+er)*rs + d0 + c4*4) = o;
    }
}

// ---------------- kernel 2: all projections via MFMA -------------------------
__global__ __launch_bounds__(256) void k_proj(
    const unsigned short* __restrict__ xb, const unsigned short* __restrict__ WqT,
    const unsigned short* __restrict__ WkT, const unsigned short* __restrict__ WvT,
    unsigned short* __restrict__ Qb, unsigned short* __restrict__ Kb,
    unsigned short* __restrict__ Vt)
{
    int z = blockIdx.z;
    int m0 = blockIdx.y*64, n0 = blockIdx.x*64;
    int tid = threadIdx.x, w = tid>>6, l15 = tid&15, g = (tid>>4)&3;
    f32x4 zf = {0.f,0.f,0.f,0.f};
    f32x4 acc[4] = {zf,zf,zf,zf};
    const unsigned short* arow = xb + (size_t)(m0+16*w+l15)*256 + 8*g;
    const unsigned short* W;
    if (z < 8)       W = WvT + (size_t)z*65536;
    else if (z == 8) W = WqT;
    else             W = WkT;
#pragma unroll
    for (int kk = 0; kk < 8; ++kk) {
        bf16x8 af = *(const bf16x8*)(arow + kk*32);
#pragma unroll
        for (int nt = 0; nt < 4; ++nt) {
            bf16x8 bf = *(const bf16x8*)(W + (size_t)(n0+16*nt+l15)*256 + kk*32 + 8*g);
            acc[nt] = __builtin_amdgcn_mfma_f32_16x16x32_bf16(af, bf, acc[nt], 0, 0, 0);
        }
    }
    if (z < 8) {                       // Vt[h*32+bsTile][e][t]
        unsigned short* VtT = Vt + ((size_t)z*32 + blockIdx.y)*(256*64);
#pragma unroll
        for (int nt = 0; nt < 4; ++nt) {
            ushort4 o = {f2bf(acc[nt][0]), f2bf(acc[nt][1]), f2bf(acc[nt][2]), f2bf(acc[nt][3])};
            *(ushort4*)(VtT + (size_t)(n0+16*nt+l15)*64 + 16*w + 4*g) = o;
        }
    } else {
        unsigned short* dst = (z == 8) ? Qb : Kb;
        int bs_base = m0 + 16*w + 4*g;
#pragma unroll
        for (int nt = 0; nt < 4; ++nt) {
            int col = n0 + 16*nt + l15;             // h*32 + kk
            int h = col>>5, kk = col&31;
#pragma unroll
            for (int j = 0; j < 4; ++j) {
                int bs = bs_base + j;
                int b = bs>>10, s = bs&1023;
                float zv = acc[nt][j];
                zv = zv > 0.f ? zv + 1.f : expf(zv);
                dst[((size_t)(h*PB+b)*PS + s)*PK + kk] = f2bf(zv);
            }
        }
    }
}

// ---------------- kernel 3: per-chunk KV sums + per-chunk K sums -------------
__global__ __launch_bounds__(256) void k_kv_sums(
    const unsigned short* __restrict__ Kb, const unsigned short* __restrict__ Vt,
    float* __restrict__ KVs, float* __restrict__ Ksum)
{
    int c = blockIdx.x, hb = blockIdx.y;
    int tid = threadIdx.x, w = tid>>6, l15 = tid&15, g = (tid>>4)&3;
    __shared__ unsigned short KT[32*72];        // K'^T [kk][t]
    __shared__ float partial[8][32];
#pragma unroll
    for (int i = 0; i < 8; ++i) {
        int flat = tid + i*256;                 // t = flat>>5, k = flat&31
        KT[(flat&31)*72 + (flat>>5)] = Kb[((size_t)hb*PS + c*64 + (flat>>5))*PK + (flat&31)];
    }
    __syncthreads();
    {
        int kk = tid & 31, part = tid >> 5;     // 8 parts x 8 t each
        float s = 0.f;
#pragma unroll
        for (int i = 0; i < 8; ++i) s += bf2f(KT[kk*72 + part*8 + i]);
        partial[part][kk] = s;
    }
    const unsigned short* Vtt = Vt + ((size_t)hb*16 + c)*(256*64);
    f32x4 zf = {0.f,0.f,0.f,0.f};
    f32x4 acc[4][2];
#pragma unroll
    for (int mt = 0; mt < 4; ++mt) { acc[mt][0] = zf; acc[mt][1] = zf; }
#pragma unroll
    for (int ks = 0; ks < 2; ++ks) {
        bf16x8 af[4];
#pragma unroll
        for (int mt = 0; mt < 4; ++mt)
            af[mt] = *(const bf16x8*)(Vtt + (size_t)(64*w + 16*mt + l15)*64 + 32*ks + 8*g);
#pragma unroll
        for (int nt = 0; nt < 2; ++nt) {
            bf16x8 bf = *(const bf16x8*)(KT + (16*nt + l15)*72 + 32*ks + 8*g);
#pragma unroll
            for (int mt = 0; mt < 4; ++mt)
                acc[mt][nt] = __builtin_amdgcn_mfma_f32_16x16x32_bf16(af[mt], bf, acc[mt][nt], 0, 0, 0);
        }
    }
    __syncthreads();
    if (tid < 32) {
        float s = 0.f;
#pragma unroll
        for (int p = 0; p < 8; ++p) s += partial[p][tid];
        Ksum[((size_t)hb*16 + c)*32 + tid] = s;
    }
    float* o = KVs + ((size_t)hb*16 + c)*8192;
#pragma unroll
    for (int mt = 0; mt < 4; ++mt)
#pragma unroll
        for (int nt = 0; nt < 2; ++nt)
#pragma unroll
            for (int j = 0; j < 4; ++j)
                o[(size_t)(64*w + 16*mt + 4*g + j)*32 + 16*nt + l15] = acc[mt][nt][j];
}

// ---------------- kernel 4: merged KV scan + den -----------------------------
// grid (48, hb): x<32 -> KV chunk-scan column x; x>=32 -> den for chunk x-32.
__global__ __launch_bounds__(256) void k_mid(
    const float* __restrict__ KVs, const float* __restrict__ Ksum,
    const unsigned short* __restrict__ Qb, const unsigned short* __restrict__ Kb,
    unsigned short* __restrict__ KVpre, float* __restrict__ den)
{
    int hb = blockIdx.y;
    int xb_ = blockIdx.x;
    __shared__ float kc[64][33];
    if (xb_ < 32) {                             // KV exclusive scan -> bf16
        int i = xb_*256 + threadIdx.x;          // 0..8191 = e*32+k
        const float* src = KVs + (size_t)hb*16*8192 + i;
        unsigned short* dst = KVpre + (size_t)hb*16*8192 + i;
        float acc = 0.f;
#pragma unroll
        for (int cc = 0; cc < 16; ++cc) { dst[cc*8192] = f2bf(acc); acc += src[cc*8192]; }
        return;
    }
    // den for chunk c
    int c = xb_ - 32;
    int tid = threadIdx.x;
    int r = tid >> 2, quad = tid & 3;           // row 0..63, 8 kk per quad
    bf16x8 k8 = *(const bf16x8*)(Kb + ((size_t)hb*PS + c*64 + r)*PK + quad*8);
#pragma unroll
    for (int i = 0; i < 8; ++i) kc[r][quad*8+i] = bf2f((unsigned short)k8[i]);
    __syncthreads();
    // Hillis-Steele inclusive scan over rows
#pragma unroll
    for (int st = 1; st < 64; st <<= 1) {
        float tmp[8];
#pragma unroll
        for (int i = 0; i < 8; ++i) tmp[i] = (r >= st) ? kc[r-st][quad*8+i] : 0.f;
        __syncthreads();
#pragma unroll
        for (int i = 0; i < 8; ++i) kc[r][quad*8+i] += tmp[i];
        __syncthreads();
    }
    float kp[8];
#pragma unroll
    for (int i = 0; i < 8; ++i) kp[i] = 0.f;
    for (int cc = 0; cc < c; ++cc) {
        const float* Ks = Ksum + ((size_t)hb*16 + cc)*32 + quad*8;
#pragma unroll
        for (int i = 0; i < 8; ++i) kp[i] += Ks[i];
    }
    bf16x8 q8 = *(const bf16x8*)(Qb + ((size_t)hb*PS + c*64 + r)*PK + quad*8);
    float p = 0.f;
#pragma unroll
    for (int i = 0; i < 8; ++i)
        p += bf2f((unsigned short)q8[i]) * (kp[i] + kc[r][quad*8+i]);
    p += __shfl_xor(p, 1);
    p += __shfl_xor(p, 2);
    if (quad == 0) den[hb*PS + c*64 + r] = p + EPS;
}

// ---------------- kernel 5: uniform att tiles + node -------------------------
// grid (17, 16, hb): x=tt<16 -> att tile (zero / MFMA / skip-diag);
//                    x==16  -> node: diag att + prior + PV -> nodeB.
__global__ __launch_bounds__(256) void k_att_node(
    const unsigned short* __restrict__ Qb, const unsigned short* __restrict__ Kb,
    const float* __restrict__ den, const unsigned short* __restrict__ Vt,
    const unsigned short* __restrict__ KVpre,
    float* __restrict__ att, unsigned short* __restrict__ nodeB)
{
    int tt = blockIdx.x, st = blockIdx.y, hb = blockIdx.z;
    int s0 = st*64;
    int tid = threadIdx.x, w = tid>>6, l15 = tid&15, g = (tid>>4)&3;
    float* attb = att + (size_t)hb*PS*PS;
    f32x4 zf = {0.f,0.f,0.f,0.f};

    __shared__ __align__(16) unsigned char smem[17664];
    float (*PT)[68] = (float(*)[68])smem;                 // 17408 (att path)
    unsigned short* PL = (unsigned short*)smem;           // 9216  (node path)
    float* rden = (float*)(smem + 17408);                 // 256

    if (tt < 16) {
        if (tt == st) return;                  // diag handled by node block
        if (tt > st) {                         // zero tile, 16 KB float4
            float4 z = {0.f,0.f,0.f,0.f};
            float* base = attb + (size_t)s0*PS + tt*64;
#pragma unroll
            for (int pp = 0; pp < 4; ++pp) {
                int f4 = tid + pp*256;
                int r = f4 >> 4, c4 = f4 & 15;
                *(float4*)(base + (size_t)r*PS + c4*4) = z;
            }
            return;
        }
        // strictly-lower tile
        if (tid < 64) rden[tid] = 1.0f / den[hb*PS + s0 + tid];
        bf16x8 qf = *(const bf16x8*)(Qb + ((size_t)hb*PS + s0 + 16*w + l15)*PK + 8*g);
        int t0 = tt*64;
        f32x4 p[4];
#pragma unroll
        for (int nt = 0; nt < 4; ++nt) {
            bf16x8 kf = *(const bf16x8*)(Kb + ((size_t)hb*PS + t0 + 16*nt + l15)*PK + 8*g);
            p[nt] = __builtin_amdgcn_mfma_f32_16x16x32_bf16(qf, kf, zf, 0, 0, 0);
        }
        __syncthreads();                       // rden ready
        float rd[4];
#pragma unroll
        for (int j = 0; j < 4; ++j) rd[j] = rden[16*w + 4*g + j];
#pragma unroll
        for (int nt = 0; nt < 4; ++nt)
#pragma unroll
            for (int j = 0; j < 4; ++j)
                PT[16*w + 4*g + j][16*nt + l15] = p[nt][j] * rd[j];
        __syncthreads();                       // PT ready
#pragma unroll
        for (int pp = 0; pp < 4; ++pp) {
            int f4 = tid + pp*256;             // r = f4>>4, c4 = f4&15
            int r = f4 >> 4, c4 = f4 & 15;
            float4 v = *(const float4*)&PT[r][c4*4];
            *(float4*)(attb + (size_t)(s0+r)*PS + t0 + c4*4) = v;
        }
        return;
    }

    // ---- node block: diag att + prior + PV -> nodeB ----
    int c = st;
    if (tid < 64) rden[tid] = 1.0f / den[hb*PS + s0 + tid];
    bf16x8 qf = *(const bf16x8*)(Qb + ((size_t)hb*PS + s0 + 16*w + l15)*PK + 8*g);
    const unsigned short* KVp = KVpre + ((size_t)hb*16 + c)*8192;
    f32x4 acc[16];
#pragma unroll
    for (int nt = 0; nt < 16; ++nt) {
        bf16x8 bf = *(const bf16x8*)(KVp + (size_t)(16*nt + l15)*32 + 8*g);
        acc[nt] = __builtin_amdgcn_mfma_f32_16x16x32_bf16(qf, bf, zf, 0, 0, 0);
    }
    f32x4 p[4];
#pragma unroll
    for (int nt4 = 0; nt4 < 4; ++nt4) {
        bf16x8 kf = *(const bf16x8*)(Kb + ((size_t)hb*PS + s0 + 16*nt4 + l15)*PK + 8*g);
        p[nt4] = __builtin_amdgcn_mfma_f32_16x16x32_bf16(qf, kf, zf, 0, 0, 0);
    }
    __syncthreads();                            // rden ready
#pragma unroll
    for (int nt4 = 0; nt4 < 4; ++nt4) {
#pragma unroll
        for (int j = 0; j < 4; ++j) {
            int r = 16*w + 4*g + j;
            int tc = 16*nt4 + l15;
            float v = p[nt4][j] * rden[r];
            if (tc > r) v = 0.f;
            attb[(size_t)(s0 + r)*PS + s0 + tc] = v;
            PL[r*72 + tc] = f2bf(v);
        }
    }
#pragma unroll
    for (int nt = 0; nt < 16; ++nt)
#pragma unroll
        for (int j = 0; j < 4; ++j)
            acc[nt][j] *= rden[16*w + 4*g + j];
    __syncthreads();                            // PL ready
    const unsigned short* Vtt = Vt + ((size_t)hb*16 + c)*(256*64);
#pragma unroll
    for (int ks = 0; ks < 2; ++ks) {
        bf16x8 af = *(const bf16x8*)(PL + (size_t)(16*w + l15)*72 + 32*ks + 8*g);
#pragma unroll
        for (int nt = 0; nt < 16; ++nt) {
            bf16x8 vf = *(const bf16x8*)(Vtt + (size_t)(16*nt + l15)*64 + 32*ks + 8*g);
            acc[nt] = __builtin_amdgcn_mfma_f32_16x16x32_bf16(af, vf, acc[nt], 0, 0, 0);
        }
    }
    int h = hb >> 1, b = hb & 1;
    unsigned short* np = nodeB + ((size_t)(b*PS + s0))*2048 + h*256;
#pragma unroll
    for (int nt = 0; nt < 16; ++nt)
#pragma unroll
        for (int j = 0; j < 4; ++j)
            np[(size_t)(16*w + 4*g + j)*2048 + 16*nt + l15] = f2bf(acc[nt][j]);
}

// ---------------- kernel 6: out = nodeB @ WoT (full K, direct store) --------
__global__ __launch_bounds__(256) void k_out2(
    const unsigned short* __restrict__ nodeB, const unsigned short* __restrict__ WoT,
    float* __restrict__ out)
{
    int e0 = blockIdx.x*64, m0 = blockIdx.y*16;
    int tid = threadIdx.x, w = tid>>6, l15 = tid&15, g = (tid>>4)&3;
    f32x4 zf = {0.f,0.f,0.f,0.f};
    f32x4 acc = zf;
    const unsigned short* arow = nodeB + (size_t)(m0 + l15)*2048 + 8*g;
    const unsigned short* brow = WoT + (size_t)(e0 + 16*w + l15)*2048 + 8*g;
#pragma unroll 8
    for (int kk = 0; kk < 64; ++kk) {
        bf16x8 af = *(const bf16x8*)(arow + kk*32);
        bf16x8 bf = *(const bf16x8*)(brow + kk*32);
        acc = __builtin_amdgcn_mfma_f32_16x16x32_bf16(af, bf, acc, 0, 0, 0);
    }
#pragma unroll
    for (int j = 0; j < 4; ++j)
        out[(size_t)(m0 + 4*g + j)*PD + e0 + 16*w + l15] = acc[j];
}

// ---------------- launch ------------------------------------------------------
extern "C" void kernel_launch(void* const* d_in, const int* in_sizes, int n_in,
                              void* d_out, int out_size, void* d_ws, size_t ws_size,
                              hipStream_t stream) {
    const float* x   = (const float*)d_in[0];
    const float* Wks = (const float*)d_in[1];
    const float* Wqs = (const float*)d_in[2];
    const float* Wvs = (const float*)d_in[3];
    const float* Wo  = (const float*)d_in[4];

    float* out = (float*)d_out;                     // [B,S,D]
    float* att = (float*)d_out + (size_t)PB*PS*PD;  // [H,B,S,S]

    // workspace layout (float offsets)
    float* ws = (float*)d_ws;
    float*          den   = ws + 0;                            //    16,384 f
    unsigned short* Qb    = (unsigned short*)(ws + 16384);     //   524,288 u16
    unsigned short* Kb    = (unsigned short*)(ws + 278528);    //   524,288 u16
    unsigned short* Vt    = (unsigned short*)(ws + 540672);    // 4,194,304 u16
    unsigned short* xb    = (unsigned short*)(ws + 2637824);   //   524,288 u16
    unsigned short* WqT   = (unsigned short*)(ws + 2899968);   //    65,536 u16
    unsigned short* WkT   = (unsigned short*)(ws + 2932736);   //    65,536 u16
    unsigned short* WvT   = (unsigned short*)(ws + 2965504);   //   524,288 u16
    unsigned short* WoT   = (unsigned short*)(ws + 3227648);   //   524,288 u16
    unsigned short* nodeB = (unsigned short*)(ws + 3489792);   // 4,194,304 u16
    float*          KVs   = ws + 5586944;                      // 2,097,152 f
    unsigned short* KVpre = (unsigned short*)(ws + 7684096);   // 2,097,152 u16
    float*          KsumG = ws + 8732672;                      //     8,192 f
    const size_t needed = (size_t)8740864 * 4;
    if (ws_size < needed) {
        fprintf(stderr, "kernel_launch: ws_size %zu < needed %zu\n", ws_size, needed);
        return;
    }

    k_prep<<<784, 256, 0, stream>>>(x, Wqs, Wks, Wvs, Wo, xb, WqT, WkT, WvT, WoT);
    k_proj<<<dim3(4, 32, 10), 256, 0, stream>>>(xb, WqT, WkT, WvT, Qb, Kb, Vt);
    k_kv_sums<<<dim3(16, HB), 256, 0, stream>>>(Kb, Vt, KVs, KsumG);
    k_mid<<<dim3(48, HB), 256, 0, stream>>>(KVs, KsumG, Qb, Kb, KVpre, den);
    k_att_node<<<dim3(17, 16, HB), 256, 0, stream>>>(Qb, Kb, den, Vt, KVpre, att, nodeB);
    k_out2<<<dim3(4, 128), 256, 0, stream>>>(nodeB, WoT, out);
}